// Round 1
// baseline (836.448 us; speedup 1.0000x reference)
//
#include <hip/hip_runtime.h>
#include <stdint.h>

#define N_NODES 200000
#define C_INN   256
#define C_MIDD  64
#define KNB     27
#define MB_TILES 3125
#define GRAM_BLOCKS 512

typedef unsigned short u16;
typedef __attribute__((ext_vector_type(8))) short short8;
typedef __attribute__((ext_vector_type(4))) float floatx4;

__device__ inline float bf2f(u16 u) {
  union { uint32_t i; float f; } v; v.i = ((uint32_t)u) << 16; return v.f;
}
__device__ inline u16 f2bf(float f) {
  union { float f; uint32_t i; } v; v.f = f;
  uint32_t lsb = (v.i >> 16) & 1u;
  uint32_t r = v.i + 0x7fffu + lsb;
  return (u16)(r >> 16);
}

// ---------------------------------------------------------------------------
// prep: zero stat accumulators; transpose+cast weights to bf16 B-operand form
//   w1t[d][k] (64x256), w2t[kn][d][c] (27x64x64), w3t[d][k] (256x64)
// ---------------------------------------------------------------------------
__global__ void prep_kernel(const float* __restrict__ W1, const float* __restrict__ W2,
                            const float* __restrict__ W3,
                            u16* __restrict__ w1t, u16* __restrict__ w2t,
                            u16* __restrict__ w3t, float* __restrict__ stats) {
  int tid = blockIdx.x * blockDim.x + threadIdx.x;
  int nth = gridDim.x * blockDim.x;
  for (int i = tid; i < 512; i += nth) stats[i] = 0.f;   // s1/ac1/s2/ac2 region
  for (int i = tid; i < 256 * 64; i += nth) {        // w1t[d*256+k] = W1[k][d]
    int d = i >> 8, k = i & 255;
    w1t[i] = f2bf(W1[k * 64 + d]);
  }
  for (int i = tid; i < 27 * 64 * 64; i += nth) {    // w2t[kn][d][c] = W2[kn][c][d]
    int kn = i >> 12, r = i & 4095, d = r >> 6, c = r & 63;
    w2t[i] = f2bf(W2[kn * 4096 + c * 64 + d]);
  }
  for (int i = tid; i < 256 * 64; i += nth) {        // w3t[d*64+k] = W3[k][d]
    int d = i >> 6, k = i & 63;
    w3t[i] = f2bf(W3[k * 256 + d]);
  }
}

// ---------------------------------------------------------------------------
// gemm1: y1[N,64] (bf16, raw pre-BN) = x[N,256] @ W1 ; fused col sum/sumsq
// ---------------------------------------------------------------------------
#define PAD1 136
__global__ __launch_bounds__(256) void gemm1_kernel(const float* __restrict__ x,
                                                    const u16* __restrict__ w1t,
                                                    u16* __restrict__ y1,
                                                    float* __restrict__ s) {
  __shared__ u16 Als[64 * PAD1];
  __shared__ u16 Bls[64 * PAD1];
  int t = threadIdx.x;
  long long rowBase = (long long)blockIdx.x * 64;
  int w = t >> 6, lane = t & 63;
  int m = lane & 15, q = lane >> 4;
  floatx4 acc[4] = {};

  for (int kh = 0; kh < 2; kh++) {
    if (kh) __syncthreads();
    #pragma unroll
    for (int j = 0; j < 8; j++) {
      int lin = j * 256 + t;
      int r = lin >> 5, c4 = lin & 31;
      floatx4 v = ((const floatx4*)x)[(rowBase + r) * 64 + kh * 32 + c4];
      ushort4 u;
      u.x = f2bf(v[0]); u.y = f2bf(v[1]); u.z = f2bf(v[2]); u.w = f2bf(v[3]);
      *(ushort4*)&Als[r * PAD1 + c4 * 4] = u;
    }
    #pragma unroll
    for (int j = 0; j < 4; j++) {
      int lin = j * 256 + t;
      int n = lin >> 4, c8 = lin & 15;
      uint4 u = ((const uint4*)w1t)[n * 32 + kh * 16 + c8];
      *(uint4*)&Bls[n * PAD1 + c8 * 8] = u;
    }
    __syncthreads();
    #pragma unroll
    for (int kc = 0; kc < 4; kc++) {
      short8 af = *(const short8*)&Als[(w * 16 + m) * PAD1 + kc * 32 + q * 8];
      #pragma unroll
      for (int tt = 0; tt < 4; tt++) {
        short8 bf = *(const short8*)&Bls[(tt * 16 + m) * PAD1 + kc * 32 + q * 8];
        acc[tt] = __builtin_amdgcn_mfma_f32_16x16x32_bf16(af, bf, acc[tt], 0, 0, 0);
      }
    }
  }
  long long base = rowBase + w * 16;
  #pragma unroll
  for (int tt = 0; tt < 4; tt++)
    #pragma unroll
    for (int r = 0; r < 4; r++)
      y1[(base + q * 4 + r) * 64 + tt * 16 + m] = f2bf(acc[tt][r]);

  // fused per-channel stats: channel = tt*16+m, rows covered by (w,q,r)
  float sv[4], qv[4];
  #pragma unroll
  for (int tt = 0; tt < 4; tt++) {
    float sl = 0.f, ql = 0.f;
    #pragma unroll
    for (int r = 0; r < 4; r++) { float v = acc[tt][r]; sl += v; ql += v * v; }
    sl += __shfl_xor(sl, 16); sl += __shfl_xor(sl, 32);
    ql += __shfl_xor(ql, 16); ql += __shfl_xor(ql, 32);
    sv[tt] = sl; qv[tt] = ql;
  }
  __syncthreads();                       // all waves done reading Als
  float* sred = (float*)Als;             // [4][64]
  float* qred = sred + 256;
  if (q == 0) {
    #pragma unroll
    for (int tt = 0; tt < 4; tt++) {
      sred[w * 64 + tt * 16 + m] = sv[tt];
      qred[w * 64 + tt * 16 + m] = qv[tt];
    }
  }
  __syncthreads();
  if (t < 64) {
    float S = 0.f, Q = 0.f;
    #pragma unroll
    for (int g = 0; g < 4; g++) { S += sred[g * 64 + t]; Q += qred[g * 64 + t]; }
    atomicAdd(&s[t], S);
    atomicAdd(&s[64 + t], Q);
  }
}

// ---------------------------------------------------------------------------
// gemm2: y2[N,64] (bf16 raw) = gather(h1, neigh) . W2 ; fused col sum/sumsq
// ---------------------------------------------------------------------------
#define PAD2 72
__global__ __launch_bounds__(256) void gemm2_kernel(const u16* __restrict__ h1,
                                                    const int* __restrict__ neigh,
                                                    const u16* __restrict__ w2t,
                                                    u16* __restrict__ y2,
                                                    float* __restrict__ s) {
  __shared__ u16 Als[64 * PAD2];
  __shared__ u16 Bls[64 * PAD2];
  __shared__ int nidx[64 * 27];
  int t = threadIdx.x;
  long long rowBase = (long long)blockIdx.x * 64;
  #pragma unroll
  for (int j = 0; j < 7; j++) {
    int lin = j * 256 + t;
    if (lin < 64 * 27) nidx[lin] = neigh[rowBase * 27 + lin];
  }
  int w = t >> 6, lane = t & 63;
  int m = lane & 15, q = lane >> 4;
  floatx4 acc[4] = {};

  for (int k = 0; k < KNB; k++) {
    __syncthreads();
    #pragma unroll
    for (int j = 0; j < 2; j++) {
      int lin = j * 256 + t;
      int r = lin >> 3, c8 = lin & 7;
      long long src = (long long)nidx[r * 27 + k] * 8 + c8;
      *(uint4*)&Als[r * PAD2 + c8 * 8] = ((const uint4*)h1)[src];
      *(uint4*)&Bls[r * PAD2 + c8 * 8] = ((const uint4*)w2t)[k * 512 + lin];
    }
    __syncthreads();
    #pragma unroll
    for (int kc = 0; kc < 2; kc++) {
      short8 af = *(const short8*)&Als[(w * 16 + m) * PAD2 + kc * 32 + q * 8];
      #pragma unroll
      for (int tt = 0; tt < 4; tt++) {
        short8 bf = *(const short8*)&Bls[(tt * 16 + m) * PAD2 + kc * 32 + q * 8];
        acc[tt] = __builtin_amdgcn_mfma_f32_16x16x32_bf16(af, bf, acc[tt], 0, 0, 0);
      }
    }
  }
  long long base = rowBase + w * 16;
  #pragma unroll
  for (int tt = 0; tt < 4; tt++)
    #pragma unroll
    for (int r = 0; r < 4; r++)
      y2[(base + q * 4 + r) * 64 + tt * 16 + m] = f2bf(acc[tt][r]);

  float sv[4], qv[4];
  #pragma unroll
  for (int tt = 0; tt < 4; tt++) {
    float sl = 0.f, ql = 0.f;
    #pragma unroll
    for (int r = 0; r < 4; r++) { float v = acc[tt][r]; sl += v; ql += v * v; }
    sl += __shfl_xor(sl, 16); sl += __shfl_xor(sl, 32);
    ql += __shfl_xor(ql, 16); ql += __shfl_xor(ql, 32);
    sv[tt] = sl; qv[tt] = ql;
  }
  __syncthreads();
  float* sred = (float*)Als;
  float* qred = sred + 256;
  if (q == 0) {
    #pragma unroll
    for (int tt = 0; tt < 4; tt++) {
      sred[w * 64 + tt * 16 + m] = sv[tt];
      qred[w * 64 + tt * 16 + m] = qv[tt];
    }
  }
  __syncthreads();
  if (t < 64) {
    float S = 0.f, Q = 0.f;
    #pragma unroll
    for (int g = 0; g < 4; g++) { S += sred[g * 64 + t]; Q += qred[g * 64 + t]; }
    atomicAdd(&s[t], S);
    atomicAdd(&s[64 + t], Q);
  }
}

// fold BN into affine: ac[c]=a, ac[C+c]=c  with  a=g*rsqrt(var+eps), c=b-mean*a
__global__ void finalize_kernel(const float* __restrict__ sums, const float* __restrict__ g,
                                const float* __restrict__ b, float* __restrict__ ac, int C) {
  int t = threadIdx.x;
  if (t < C) {
    float inv = 1.f / (float)N_NODES;
    float mean = sums[t] * inv;
    float var = sums[C + t] * inv - mean * mean;
    float a = g[t] * rsqrtf(var + 1e-3f);
    ac[t] = a;
    ac[C + t] = b[t] - mean * a;
  }
}

// in-place bf16 BN+ReLU for C=64 buffers
__global__ __launch_bounds__(256) void apply_bn_relu_kernel(u16* __restrict__ y,
                                                            const float* __restrict__ ac) {
  __shared__ float a[64], cc[64];
  int t = threadIdx.x;
  if (t < 64) { a[t] = ac[t]; cc[t] = ac[64 + t]; }
  __syncthreads();
  const long long total = (long long)N_NODES * 64 / 8;
  for (long long i = (long long)blockIdx.x * 256 + t; i < total;
       i += (long long)gridDim.x * 256) {
    uint4 u = ((uint4*)y)[i];
    int c0 = (int)((i & 7) * 8);
    u16* us = (u16*)&u;
    #pragma unroll
    for (int j = 0; j < 8; j++) {
      float v = bf2f(us[j]);
      v = fmaf(a[c0 + j], v, cc[c0 + j]);
      us[j] = f2bf(fmaxf(v, 0.f));
    }
    ((uint4*)y)[i] = u;
  }
}

// ---------------------------------------------------------------------------
// gram: per-block partials of G = h2n^T h2n (64x64) and colsum(h2n) (64)
// Each block processes 64-row tiles grid-strided; MFMA on transposed LDS tile.
// ---------------------------------------------------------------------------
#define PADG 72
__global__ __launch_bounds__(256) void gram_kernel(const u16* __restrict__ h2,
                                                   float* __restrict__ Gpart,
                                                   float* __restrict__ cspart) {
  __shared__ u16 T[64 * PADG];       // T[c][r] transposed tile
  int t = threadIdx.x;
  int w = t >> 6, lane = t & 63;
  int m = lane & 15, q = lane >> 4;
  const int c8 = t & 7;              // fixed channel-octet per thread
  floatx4 acc[4] = {};
  float csl[8] = {};
  for (int tile = blockIdx.x; tile < MB_TILES; tile += gridDim.x) {
    __syncthreads();
    #pragma unroll
    for (int j = 0; j < 2; j++) {
      int lin = j * 256 + t;
      int r = lin >> 3;
      uint4 u = ((const uint4*)h2)[(long long)tile * 512 + lin];
      u16* us = (u16*)&u;
      #pragma unroll
      for (int e = 0; e < 8; e++) {
        csl[e] += bf2f(us[e]);
        T[(c8 * 8 + e) * PADG + r] = us[e];
      }
    }
    __syncthreads();
    #pragma unroll
    for (int kc = 0; kc < 2; kc++) {
      short8 af = *(const short8*)&T[(w * 16 + m) * PADG + kc * 32 + q * 8];
      #pragma unroll
      for (int tt = 0; tt < 4; tt++) {
        short8 bf = *(const short8*)&T[(tt * 16 + m) * PADG + kc * 32 + q * 8];
        acc[tt] = __builtin_amdgcn_mfma_f32_16x16x32_bf16(af, bf, acc[tt], 0, 0, 0);
      }
    }
  }
  long long b = blockIdx.x;
  #pragma unroll
  for (int tt = 0; tt < 4; tt++)
    #pragma unroll
    for (int r = 0; r < 4; r++)
      Gpart[b * 4096 + (w * 16 + q * 4 + r) * 64 + tt * 16 + m] = acc[tt][r];
  __syncthreads();
  float* cred = (float*)T;           // 256*8 floats = 8 KB
  #pragma unroll
  for (int e = 0; e < 8; e++) cred[t * 8 + e] = csl[e];
  __syncthreads();
  if (t < 64) {
    float S = 0.f;
    for (int g = 0; g < 32; g++) S += cred[((g << 3) | (t >> 3)) * 8 + (t & 7)];
    cspart[b * 64 + t] = S;
  }
}

// reduce gram partials: G[4096], cs[64]
__global__ void greduce_kernel(const float* __restrict__ Gpart,
                               const float* __restrict__ cspart,
                               float* __restrict__ G, float* __restrict__ cs) {
  int idx = blockIdx.x * 64 + threadIdx.x;
  if (idx < 4096) {
    float S = 0.f;
    for (int b = 0; b < GRAM_BLOCKS; b++) S += Gpart[b * 4096 + idx];
    G[idx] = S;
  } else if (idx < 4160) {
    int c = idx - 4096;
    float S = 0.f;
    for (int b = 0; b < GRAM_BLOCKS; b++) S += cspart[b * 64 + c];
    cs[c] = S;
  }
}

// BN3 stats without materializing y3:
//   mean_c = (cs . w3_c)/N ;  sumsq_c = w3_c^T G w3_c ; var = sumsq/N - mean^2
__global__ void finalize3_kernel(const float* __restrict__ G, const float* __restrict__ cs,
                                 const u16* __restrict__ w3t, const float* __restrict__ g3,
                                 const float* __restrict__ b3, float* __restrict__ ac3) {
  __shared__ float Gs[4096];
  __shared__ float css[64];
  int t = threadIdx.x;
  for (int i = t; i < 4096; i += 256) Gs[i] = G[i];
  if (t < 64) css[t] = cs[t];
  __syncthreads();
  float wv[64];
  #pragma unroll
  for (int k = 0; k < 64; k++) wv[k] = bf2f(w3t[t * 64 + k]);  // W3[k][c=t] (bf16-rounded)
  const float invN = 1.f / (float)N_NODES;
  float mean = 0.f;
  #pragma unroll
  for (int k = 0; k < 64; k++) mean += css[k] * wv[k];
  mean *= invN;
  float qf = 0.f;
  #pragma unroll
  for (int k = 0; k < 64; k++) {
    float tmp = 0.f;
    #pragma unroll
    for (int k2 = 0; k2 < 64; k2++) tmp += Gs[k * 64 + k2] * wv[k2];
    qf += wv[k] * tmp;
  }
  float var = qf * invN - mean * mean;
  float a = g3[t] * rsqrtf(var + 1e-3f);
  ac3[t] = a;
  ac3[256 + t] = b3[t] - mean * a;
}

// ---------------------------------------------------------------------------
// gemm3e: out = relu(BN3(h2n @ W3) + x)  — fused, y3 never materialized
// ---------------------------------------------------------------------------
#define PAD3 72
__global__ __launch_bounds__(256) void gemm3e_kernel(const u16* __restrict__ h2,
                                                     const u16* __restrict__ w3t,
                                                     const float* __restrict__ ac,
                                                     const float* __restrict__ x,
                                                     float* __restrict__ out) {
  __shared__ u16 Als[64 * PAD3];
  __shared__ u16 Bls[256 * PAD3];
  __shared__ float aS[256], cS[256];
  int t = threadIdx.x;
  aS[t] = ac[t]; cS[t] = ac[256 + t];
  long long rowBase = (long long)blockIdx.x * 64;
  #pragma unroll
  for (int j = 0; j < 2; j++) {   // A: 64x64 bf16 = 512 chunks
    int lin = j * 256 + t;
    int r = lin >> 3, c8 = lin & 7;
    *(uint4*)&Als[r * PAD3 + c8 * 8] = ((const uint4*)h2)[rowBase * 8 + lin];
  }
  #pragma unroll
  for (int j = 0; j < 8; j++) {   // B: 256x64 bf16 = 2048 chunks
    int lin = j * 256 + t;
    int n = lin >> 3, c8 = lin & 7;
    *(uint4*)&Bls[n * PAD3 + c8 * 8] = ((const uint4*)w3t)[lin];
  }
  __syncthreads();
  int w = t >> 6, lane = t & 63;
  int m = lane & 15, q = lane >> 4;
  floatx4 acc[16] = {};
  short8 af0 = *(const short8*)&Als[(w * 16 + m) * PAD3 + q * 8];
  short8 af1 = *(const short8*)&Als[(w * 16 + m) * PAD3 + 32 + q * 8];
  #pragma unroll
  for (int tt = 0; tt < 16; tt++) {
    short8 b0 = *(const short8*)&Bls[(tt * 16 + m) * PAD3 + q * 8];
    short8 b1 = *(const short8*)&Bls[(tt * 16 + m) * PAD3 + 32 + q * 8];
    acc[tt] = __builtin_amdgcn_mfma_f32_16x16x32_bf16(af0, b0, acc[tt], 0, 0, 0);
    acc[tt] = __builtin_amdgcn_mfma_f32_16x16x32_bf16(af1, b1, acc[tt], 0, 0, 0);
  }
  long long base = rowBase + w * 16;
  #pragma unroll
  for (int r = 0; r < 4; r++) {
    long long row = base + q * 4 + r;
    #pragma unroll
    for (int tt = 0; tt < 16; tt++) {
      int col = tt * 16 + m;
      float v = fmaf(aS[col], acc[tt][r], cS[col]) + x[row * 256 + col];
      out[row * 256 + col] = fmaxf(v, 0.f);
    }
  }
}

// ---------------------------------------------------------------------------
extern "C" void kernel_launch(void* const* d_in, const int* in_sizes, int n_in,
                              void* d_out, int out_size, void* d_ws, size_t ws_size,
                              hipStream_t stream) {
  (void)in_sizes; (void)n_in; (void)out_size; (void)ws_size;
  const float* x  = (const float*)d_in[0];
  const int* neigh = (const int*)d_in[1];
  const float* W1 = (const float*)d_in[3];
  const float* g1 = (const float*)d_in[4];
  const float* b1 = (const float*)d_in[5];
  const float* W2 = (const float*)d_in[6];
  const float* g2 = (const float*)d_in[7];
  const float* b2 = (const float*)d_in[8];
  const float* W3 = (const float*)d_in[9];
  const float* g3 = (const float*)d_in[10];
  const float* b3 = (const float*)d_in[11];

  char* ws = (char*)d_ws;
  u16* h1  = (u16*)(ws);                          // N*64 bf16 = 25,600,000 B
  u16* h2  = (u16*)(ws + 25600000LL);             // N*64 bf16
  u16* w1t = (u16*)(ws + 51200000LL);             // 32,768 B
  u16* w2t = (u16*)(ws + 51232768LL);             // 221,184 B
  u16* w3t = (u16*)(ws + 51453952LL);             // 32,768 B
  float* stats = (float*)(ws + 51486720LL);       // 5184 floats
  float* s1  = stats,       *ac1 = stats + 128;
  float* s2  = stats + 256, *ac2 = stats + 384;
  float* G   = stats + 512;                       // 4096
  float* cs3 = stats + 4608;                      // 64
  float* ac3 = stats + 4672;                      // 512
  float* Gpart  = (float*)(ws + 51507456LL);      // 512*4096*4 = 8,388,608 B
  float* cspart = (float*)(ws + 59896064LL);      // 512*64*4 = 131,072 B
  float* out = (float*)d_out;

  prep_kernel<<<256, 256, 0, stream>>>(W1, W2, W3, w1t, w2t, w3t, stats);

  gemm1_kernel<<<MB_TILES, 256, 0, stream>>>(x, w1t, h1, s1);
  finalize_kernel<<<1, 256, 0, stream>>>(s1, g1, b1, ac1, 64);
  apply_bn_relu_kernel<<<2048, 256, 0, stream>>>(h1, ac1);

  gemm2_kernel<<<MB_TILES, 256, 0, stream>>>(h1, neigh, w2t, h2, s2);
  finalize_kernel<<<1, 256, 0, stream>>>(s2, g2, b2, ac2, 64);
  apply_bn_relu_kernel<<<2048, 256, 0, stream>>>(h2, ac2);

  gram_kernel<<<GRAM_BLOCKS, 256, 0, stream>>>(h2, Gpart, cspart);
  greduce_kernel<<<65, 64, 0, stream>>>(Gpart, cspart, G, cs3);
  finalize3_kernel<<<1, 256, 0, stream>>>(G, cs3, w3t, g3, b3, ac3);
  gemm3e_kernel<<<MB_TILES, 256, 0, stream>>>(h2, w3t, ac3, x, out);
}

// Round 2
// 691.530 us; speedup vs baseline: 1.2096x; 1.2096x over previous
//
#include <hip/hip_runtime.h>
#include <stdint.h>

#define N_NODES 200000
#define C_INN   256
#define C_MIDD  64
#define KNB     27
#define MB_TILES 3125
#define GRAM_BLOCKS 512

typedef unsigned short u16;
typedef __attribute__((ext_vector_type(8))) short short8;
typedef __attribute__((ext_vector_type(4))) float floatx4;

__device__ inline float bf2f(u16 u) {
  union { uint32_t i; float f; } v; v.i = ((uint32_t)u) << 16; return v.f;
}
__device__ inline u16 f2bf(float f) {
  union { float f; uint32_t i; } v; v.f = f;
  uint32_t lsb = (v.i >> 16) & 1u;
  uint32_t r = v.i + 0x7fffu + lsb;
  return (u16)(r >> 16);
}

// ---------------------------------------------------------------------------
// prep: zero stat accumulators; transpose+cast weights to bf16 B-operand form
//   w1t[d][k] (64x256), w2t[kn][d][c] (27x64x64), w3t[d][k] (256x64)
// ---------------------------------------------------------------------------
__global__ void prep_kernel(const float* __restrict__ W1, const float* __restrict__ W2,
                            const float* __restrict__ W3,
                            u16* __restrict__ w1t, u16* __restrict__ w2t,
                            u16* __restrict__ w3t, float* __restrict__ stats) {
  int tid = blockIdx.x * blockDim.x + threadIdx.x;
  int nth = gridDim.x * blockDim.x;
  for (int i = tid; i < 512; i += nth) stats[i] = 0.f;   // s1/ac1/s2/ac2 region
  for (int i = tid; i < 256 * 64; i += nth) {        // w1t[d*256+k] = W1[k][d]
    int d = i >> 8, k = i & 255;
    w1t[i] = f2bf(W1[k * 64 + d]);
  }
  for (int i = tid; i < 27 * 64 * 64; i += nth) {    // w2t[kn][d][c] = W2[kn][c][d]
    int kn = i >> 12, r = i & 4095, d = r >> 6, c = r & 63;
    w2t[i] = f2bf(W2[kn * 4096 + c * 64 + d]);
  }
  for (int i = tid; i < 256 * 64; i += nth) {        // w3t[d*64+k] = W3[k][d]
    int d = i >> 6, k = i & 63;
    w3t[i] = f2bf(W3[k * 256 + d]);
  }
}

// ---------------------------------------------------------------------------
// gemm1: y1[N,64] (bf16, raw pre-BN) = x[N,256] @ W1 ; fused col sum/sumsq
// ---------------------------------------------------------------------------
#define PAD1 136
__global__ __launch_bounds__(256) void gemm1_kernel(const float* __restrict__ x,
                                                    const u16* __restrict__ w1t,
                                                    u16* __restrict__ y1,
                                                    float* __restrict__ s) {
  __shared__ u16 Als[64 * PAD1];
  __shared__ u16 Bls[64 * PAD1];
  int t = threadIdx.x;
  long long rowBase = (long long)blockIdx.x * 64;
  int w = t >> 6, lane = t & 63;
  int m = lane & 15, q = lane >> 4;
  floatx4 acc[4] = {};

  for (int kh = 0; kh < 2; kh++) {
    if (kh) __syncthreads();
    #pragma unroll
    for (int j = 0; j < 8; j++) {
      int lin = j * 256 + t;
      int r = lin >> 5, c4 = lin & 31;
      floatx4 v = ((const floatx4*)x)[(rowBase + r) * 64 + kh * 32 + c4];
      ushort4 u;
      u.x = f2bf(v[0]); u.y = f2bf(v[1]); u.z = f2bf(v[2]); u.w = f2bf(v[3]);
      *(ushort4*)&Als[r * PAD1 + c4 * 4] = u;
    }
    #pragma unroll
    for (int j = 0; j < 4; j++) {
      int lin = j * 256 + t;
      int n = lin >> 4, c8 = lin & 15;
      uint4 u = ((const uint4*)w1t)[n * 32 + kh * 16 + c8];
      *(uint4*)&Bls[n * PAD1 + c8 * 8] = u;
    }
    __syncthreads();
    #pragma unroll
    for (int kc = 0; kc < 4; kc++) {
      short8 af = *(const short8*)&Als[(w * 16 + m) * PAD1 + kc * 32 + q * 8];
      #pragma unroll
      for (int tt = 0; tt < 4; tt++) {
        short8 bf = *(const short8*)&Bls[(tt * 16 + m) * PAD1 + kc * 32 + q * 8];
        acc[tt] = __builtin_amdgcn_mfma_f32_16x16x32_bf16(af, bf, acc[tt], 0, 0, 0);
      }
    }
  }
  long long base = rowBase + w * 16;
  #pragma unroll
  for (int tt = 0; tt < 4; tt++)
    #pragma unroll
    for (int r = 0; r < 4; r++)
      y1[(base + q * 4 + r) * 64 + tt * 16 + m] = f2bf(acc[tt][r]);

  // fused per-channel stats: channel = tt*16+m, rows covered by (w,q,r)
  float sv[4], qv[4];
  #pragma unroll
  for (int tt = 0; tt < 4; tt++) {
    float sl = 0.f, ql = 0.f;
    #pragma unroll
    for (int r = 0; r < 4; r++) { float v = acc[tt][r]; sl += v; ql += v * v; }
    sl += __shfl_xor(sl, 16); sl += __shfl_xor(sl, 32);
    ql += __shfl_xor(ql, 16); ql += __shfl_xor(ql, 32);
    sv[tt] = sl; qv[tt] = ql;
  }
  __syncthreads();                       // all waves done reading Als
  float* sred = (float*)Als;             // [4][64]
  float* qred = sred + 256;
  if (q == 0) {
    #pragma unroll
    for (int tt = 0; tt < 4; tt++) {
      sred[w * 64 + tt * 16 + m] = sv[tt];
      qred[w * 64 + tt * 16 + m] = qv[tt];
    }
  }
  __syncthreads();
  if (t < 64) {
    float S = 0.f, Q = 0.f;
    #pragma unroll
    for (int g = 0; g < 4; g++) { S += sred[g * 64 + t]; Q += qred[g * 64 + t]; }
    atomicAdd(&s[t], S);
    atomicAdd(&s[64 + t], Q);
  }
}

// ---------------------------------------------------------------------------
// gemm2: y2[N,64] (bf16 raw) = gather(h1, neigh) . W2 ; fused col sum/sumsq
// ---------------------------------------------------------------------------
#define PAD2 72
__global__ __launch_bounds__(256) void gemm2_kernel(const u16* __restrict__ h1,
                                                    const int* __restrict__ neigh,
                                                    const u16* __restrict__ w2t,
                                                    u16* __restrict__ y2,
                                                    float* __restrict__ s) {
  __shared__ u16 Als[64 * PAD2];
  __shared__ u16 Bls[64 * PAD2];
  __shared__ int nidx[64 * 27];
  int t = threadIdx.x;
  long long rowBase = (long long)blockIdx.x * 64;
  #pragma unroll
  for (int j = 0; j < 7; j++) {
    int lin = j * 256 + t;
    if (lin < 64 * 27) nidx[lin] = neigh[rowBase * 27 + lin];
  }
  int w = t >> 6, lane = t & 63;
  int m = lane & 15, q = lane >> 4;
  floatx4 acc[4] = {};

  for (int k = 0; k < KNB; k++) {
    __syncthreads();
    #pragma unroll
    for (int j = 0; j < 2; j++) {
      int lin = j * 256 + t;
      int r = lin >> 3, c8 = lin & 7;
      long long src = (long long)nidx[r * 27 + k] * 8 + c8;
      *(uint4*)&Als[r * PAD2 + c8 * 8] = ((const uint4*)h1)[src];
      *(uint4*)&Bls[r * PAD2 + c8 * 8] = ((const uint4*)w2t)[k * 512 + lin];
    }
    __syncthreads();
    #pragma unroll
    for (int kc = 0; kc < 2; kc++) {
      short8 af = *(const short8*)&Als[(w * 16 + m) * PAD2 + kc * 32 + q * 8];
      #pragma unroll
      for (int tt = 0; tt < 4; tt++) {
        short8 bf = *(const short8*)&Bls[(tt * 16 + m) * PAD2 + kc * 32 + q * 8];
        acc[tt] = __builtin_amdgcn_mfma_f32_16x16x32_bf16(af, bf, acc[tt], 0, 0, 0);
      }
    }
  }
  long long base = rowBase + w * 16;
  #pragma unroll
  for (int tt = 0; tt < 4; tt++)
    #pragma unroll
    for (int r = 0; r < 4; r++)
      y2[(base + q * 4 + r) * 64 + tt * 16 + m] = f2bf(acc[tt][r]);

  float sv[4], qv[4];
  #pragma unroll
  for (int tt = 0; tt < 4; tt++) {
    float sl = 0.f, ql = 0.f;
    #pragma unroll
    for (int r = 0; r < 4; r++) { float v = acc[tt][r]; sl += v; ql += v * v; }
    sl += __shfl_xor(sl, 16); sl += __shfl_xor(sl, 32);
    ql += __shfl_xor(ql, 16); ql += __shfl_xor(ql, 32);
    sv[tt] = sl; qv[tt] = ql;
  }
  __syncthreads();
  float* sred = (float*)Als;
  float* qred = sred + 256;
  if (q == 0) {
    #pragma unroll
    for (int tt = 0; tt < 4; tt++) {
      sred[w * 64 + tt * 16 + m] = sv[tt];
      qred[w * 64 + tt * 16 + m] = qv[tt];
    }
  }
  __syncthreads();
  if (t < 64) {
    float S = 0.f, Q = 0.f;
    #pragma unroll
    for (int g = 0; g < 4; g++) { S += sred[g * 64 + t]; Q += qred[g * 64 + t]; }
    atomicAdd(&s[t], S);
    atomicAdd(&s[64 + t], Q);
  }
}

// fold BN into affine: ac[c]=a, ac[C+c]=c  with  a=g*rsqrt(var+eps), c=b-mean*a
__global__ void finalize_kernel(const float* __restrict__ sums, const float* __restrict__ g,
                                const float* __restrict__ b, float* __restrict__ ac, int C) {
  int t = threadIdx.x;
  if (t < C) {
    float inv = 1.f / (float)N_NODES;
    float mean = sums[t] * inv;
    float var = sums[C + t] * inv - mean * mean;
    float a = g[t] * rsqrtf(var + 1e-3f);
    ac[t] = a;
    ac[C + t] = b[t] - mean * a;
  }
}

// in-place bf16 BN+ReLU for C=64 buffers
__global__ __launch_bounds__(256) void apply_bn_relu_kernel(u16* __restrict__ y,
                                                            const float* __restrict__ ac) {
  __shared__ float a[64], cc[64];
  int t = threadIdx.x;
  if (t < 64) { a[t] = ac[t]; cc[t] = ac[64 + t]; }
  __syncthreads();
  const long long total = (long long)N_NODES * 64 / 8;
  for (long long i = (long long)blockIdx.x * 256 + t; i < total;
       i += (long long)gridDim.x * 256) {
    uint4 u = ((uint4*)y)[i];
    int c0 = (int)((i & 7) * 8);
    u16* us = (u16*)&u;
    #pragma unroll
    for (int j = 0; j < 8; j++) {
      float v = bf2f(us[j]);
      v = fmaf(a[c0 + j], v, cc[c0 + j]);
      us[j] = f2bf(fmaxf(v, 0.f));
    }
    ((uint4*)y)[i] = u;
  }
}

// ---------------------------------------------------------------------------
// gram: per-block partials of G = h2n^T h2n (64x64) and colsum(h2n) (64)
// ---------------------------------------------------------------------------
#define PADG 72
__global__ __launch_bounds__(256) void gram_kernel(const u16* __restrict__ h2,
                                                   float* __restrict__ Gpart,
                                                   float* __restrict__ cspart) {
  __shared__ u16 T[64 * PADG];       // T[c][r] transposed tile
  int t = threadIdx.x;
  int w = t >> 6, lane = t & 63;
  int m = lane & 15, q = lane >> 4;
  const int c8 = t & 7;              // fixed channel-octet per thread
  floatx4 acc[4] = {};
  float csl[8] = {};
  for (int tile = blockIdx.x; tile < MB_TILES; tile += gridDim.x) {
    __syncthreads();
    #pragma unroll
    for (int j = 0; j < 2; j++) {
      int lin = j * 256 + t;
      int r = lin >> 3;
      uint4 u = ((const uint4*)h2)[(long long)tile * 512 + lin];
      u16* us = (u16*)&u;
      #pragma unroll
      for (int e = 0; e < 8; e++) {
        csl[e] += bf2f(us[e]);
        T[(c8 * 8 + e) * PADG + r] = us[e];
      }
    }
    __syncthreads();
    #pragma unroll
    for (int kc = 0; kc < 2; kc++) {
      short8 af = *(const short8*)&T[(w * 16 + m) * PADG + kc * 32 + q * 8];
      #pragma unroll
      for (int tt = 0; tt < 4; tt++) {
        short8 bf = *(const short8*)&T[(tt * 16 + m) * PADG + kc * 32 + q * 8];
        acc[tt] = __builtin_amdgcn_mfma_f32_16x16x32_bf16(af, bf, acc[tt], 0, 0, 0);
      }
    }
  }
  long long b = blockIdx.x;
  #pragma unroll
  for (int tt = 0; tt < 4; tt++)
    #pragma unroll
    for (int r = 0; r < 4; r++)
      Gpart[b * 4096 + (w * 16 + q * 4 + r) * 64 + tt * 16 + m] = acc[tt][r];
  __syncthreads();
  float* cred = (float*)T;           // 256*8 floats = 8 KB
  #pragma unroll
  for (int e = 0; e < 8; e++) cred[t * 8 + e] = csl[e];
  __syncthreads();
  if (t < 64) {
    float S = 0.f;
    for (int g = 0; g < 32; g++) S += cred[((g << 3) | (t >> 3)) * 8 + (t & 7)];
    cspart[b * 64 + t] = S;
  }
}

// reduce gram partials: G[4096], cs[64]
__global__ void greduce_kernel(const float* __restrict__ Gpart,
                               const float* __restrict__ cspart,
                               float* __restrict__ G, float* __restrict__ cs) {
  int idx = blockIdx.x * 64 + threadIdx.x;
  if (idx < 4096) {
    float S = 0.f;
    for (int b = 0; b < GRAM_BLOCKS; b++) S += Gpart[b * 4096 + idx];
    G[idx] = S;
  } else if (idx < 4160) {
    int c = idx - 4096;
    float S = 0.f;
    for (int b = 0; b < GRAM_BLOCKS; b++) S += cspart[b * 64 + c];
    cs[c] = S;
  }
}

// BN3 stats without materializing y3:
//   mean_c = (cs . w3_c)/N ;  sumsq_c = w3_c^T G w3_c ; var = sumsq/N - mean^2
__global__ void finalize3_kernel(const float* __restrict__ G, const float* __restrict__ cs,
                                 const u16* __restrict__ w3t, const float* __restrict__ g3,
                                 const float* __restrict__ b3, float* __restrict__ ac3) {
  __shared__ float Gs[4096];
  __shared__ float css[64];
  int t = threadIdx.x;
  for (int i = t; i < 4096; i += 256) Gs[i] = G[i];
  if (t < 64) css[t] = cs[t];
  __syncthreads();
  float wv[64];
  #pragma unroll
  for (int k = 0; k < 64; k++) wv[k] = bf2f(w3t[t * 64 + k]);  // W3[k][c=t] (bf16-rounded)
  const float invN = 1.f / (float)N_NODES;
  float mean = 0.f;
  #pragma unroll
  for (int k = 0; k < 64; k++) mean += css[k] * wv[k];
  mean *= invN;
  float qf = 0.f;
  #pragma unroll
  for (int k = 0; k < 64; k++) {
    float tmp = 0.f;
    #pragma unroll
    for (int k2 = 0; k2 < 64; k2++) tmp += Gs[k * 64 + k2] * wv[k2];
    qf += wv[k] * tmp;
  }
  float var = qf * invN - mean * mean;
  float a = g3[t] * rsqrtf(var + 1e-3f);
  ac3[t] = a;
  ac3[256 + t] = b3[t] - mean * a;
}

// ---------------------------------------------------------------------------
// gemm3e: out = relu(BN3(h2n @ W3) + x)  — fused, y3 never materialized.
// MFMA operands SWAPPED so acc[tt][r] = C[row = w*16+m][col = tt*16+q*4+r]:
// per-thread row is fixed -> float4 x-load / out-store epilogue (was 128
// scalar VMEM ops per thread; latency-bound at 17% HBM).
// ---------------------------------------------------------------------------
#define PAD3 72
__global__ __launch_bounds__(256) void gemm3e_kernel(const u16* __restrict__ h2,
                                                     const u16* __restrict__ w3t,
                                                     const float* __restrict__ ac,
                                                     const float* __restrict__ x,
                                                     float* __restrict__ out) {
  __shared__ u16 Als[64 * PAD3];
  __shared__ u16 Bls[256 * PAD3];
  __shared__ __align__(16) float aS[256];
  __shared__ __align__(16) float cS[256];
  int t = threadIdx.x;
  aS[t] = ac[t]; cS[t] = ac[256 + t];
  long long rowBase = (long long)blockIdx.x * 64;
  #pragma unroll
  for (int j = 0; j < 2; j++) {   // A: 64x64 bf16 = 512 chunks
    int lin = j * 256 + t;
    int r = lin >> 3, c8 = lin & 7;
    *(uint4*)&Als[r * PAD3 + c8 * 8] = ((const uint4*)h2)[rowBase * 8 + lin];
  }
  #pragma unroll
  for (int j = 0; j < 8; j++) {   // B: 256x64 bf16 = 2048 chunks
    int lin = j * 256 + t;
    int n = lin >> 3, c8 = lin & 7;
    *(uint4*)&Bls[n * PAD3 + c8 * 8] = ((const uint4*)w3t)[lin];
  }
  __syncthreads();
  int w = t >> 6, lane = t & 63;
  int m = lane & 15, q = lane >> 4;
  floatx4 acc[16] = {};
  short8 af0 = *(const short8*)&Als[(w * 16 + m) * PAD3 + q * 8];
  short8 af1 = *(const short8*)&Als[(w * 16 + m) * PAD3 + 32 + q * 8];
  #pragma unroll
  for (int tt = 0; tt < 16; tt++) {
    short8 b0 = *(const short8*)&Bls[(tt * 16 + m) * PAD3 + q * 8];
    short8 b1 = *(const short8*)&Bls[(tt * 16 + m) * PAD3 + 32 + q * 8];
    // swapped operands: D' = Bls-rows x Als-rows -> transposed fragment layout
    acc[tt] = __builtin_amdgcn_mfma_f32_16x16x32_bf16(b0, af0, acc[tt], 0, 0, 0);
    acc[tt] = __builtin_amdgcn_mfma_f32_16x16x32_bf16(b1, af1, acc[tt], 0, 0, 0);
  }
  // epilogue: row fixed per thread; 16 x {float4 load x, fma, float4 store}
  long long row = rowBase + w * 16 + m;
  const floatx4* xr = (const floatx4*)x + row * 64;
  floatx4* outr = (floatx4*)out + row * 64;
  const floatx4* a4 = (const floatx4*)aS;
  const floatx4* c4 = (const floatx4*)cS;
  #pragma unroll
  for (int tt = 0; tt < 16; tt++) {
    int cq = tt * 4 + q;                 // float4 index within row (cols cq*4..cq*4+3)
    floatx4 xa = xr[cq];
    floatx4 av = a4[cq];
    floatx4 cv = c4[cq];
    floatx4 v;
    #pragma unroll
    for (int j = 0; j < 4; j++)
      v[j] = fmaxf(fmaf(av[j], acc[tt][j], cv[j]) + xa[j], 0.f);
    outr[cq] = v;
  }
}

// ---------------------------------------------------------------------------
extern "C" void kernel_launch(void* const* d_in, const int* in_sizes, int n_in,
                              void* d_out, int out_size, void* d_ws, size_t ws_size,
                              hipStream_t stream) {
  (void)in_sizes; (void)n_in; (void)out_size; (void)ws_size;
  const float* x  = (const float*)d_in[0];
  const int* neigh = (const int*)d_in[1];
  const float* W1 = (const float*)d_in[3];
  const float* g1 = (const float*)d_in[4];
  const float* b1 = (const float*)d_in[5];
  const float* W2 = (const float*)d_in[6];
  const float* g2 = (const float*)d_in[7];
  const float* b2 = (const float*)d_in[8];
  const float* W3 = (const float*)d_in[9];
  const float* g3 = (const float*)d_in[10];
  const float* b3 = (const float*)d_in[11];

  char* ws = (char*)d_ws;
  u16* h1  = (u16*)(ws);                          // N*64 bf16 = 25,600,000 B
  u16* h2  = (u16*)(ws + 25600000LL);             // N*64 bf16
  u16* w1t = (u16*)(ws + 51200000LL);             // 32,768 B
  u16* w2t = (u16*)(ws + 51232768LL);             // 221,184 B
  u16* w3t = (u16*)(ws + 51453952LL);             // 32,768 B
  float* stats = (float*)(ws + 51486720LL);       // 5184 floats
  float* s1  = stats,       *ac1 = stats + 128;
  float* s2  = stats + 256, *ac2 = stats + 384;
  float* G   = stats + 512;                       // 4096
  float* cs3 = stats + 4608;                      // 64
  float* ac3 = stats + 4672;                      // 512
  float* Gpart  = (float*)(ws + 51507456LL);      // 512*4096*4 = 8,388,608 B
  float* cspart = (float*)(ws + 59896064LL);      // 512*64*4 = 131,072 B
  float* out = (float*)d_out;

  prep_kernel<<<256, 256, 0, stream>>>(W1, W2, W3, w1t, w2t, w3t, stats);

  gemm1_kernel<<<MB_TILES, 256, 0, stream>>>(x, w1t, h1, s1);
  finalize_kernel<<<1, 256, 0, stream>>>(s1, g1, b1, ac1, 64);
  apply_bn_relu_kernel<<<2048, 256, 0, stream>>>(h1, ac1);

  gemm2_kernel<<<MB_TILES, 256, 0, stream>>>(h1, neigh, w2t, h2, s2);
  finalize_kernel<<<1, 256, 0, stream>>>(s2, g2, b2, ac2, 64);
  apply_bn_relu_kernel<<<2048, 256, 0, stream>>>(h2, ac2);

  gram_kernel<<<GRAM_BLOCKS, 256, 0, stream>>>(h2, Gpart, cspart);
  greduce_kernel<<<65, 64, 0, stream>>>(Gpart, cspart, G, cs3);
  finalize3_kernel<<<1, 256, 0, stream>>>(G, cs3, w3t, g3, b3, ac3);
  gemm3e_kernel<<<MB_TILES, 256, 0, stream>>>(h2, w3t, ac3, x, out);
}